// Round 10
// baseline (351.371 us; speedup 1.0000x reference)
//
#include <hip/hip_runtime.h>
#include <hip/hip_bf16.h>
#include <math.h>

// Problem constants
#define B_    1024
#define S_    256
#define COV_  512
#define H_    128
#define E_    8
#define ES_   7

// ws layout (floats)
#define W_WS_OFF   0                       // [3][1024][8]
#define COVG_OFF   24576                   // [3][1024][128]
#define USAGE_OFF  417792                  // [3][128][8] per-router-block partials

typedef __attribute__((ext_vector_type(8))) short bf16x8;  // 8 bf16 = 4 VGPRs (MFMA A/B frag)
typedef __attribute__((ext_vector_type(4))) float f32x4;   // MFMA C/D frag

// Fast softplus: 2 HW transcendentals (v_exp_f32 / v_log_f32) + few VALU.
__device__ __forceinline__ float softplus_f(float x) {
    return fmaxf(x, 0.0f) + __logf(1.0f + __expf(-fabsf(x)));
}

// v_cvt_pk_bf16_f32: pack two fp32 -> two bf16 (RNE).
__device__ __forceinline__ unsigned pk2_bf16(float a, float b) {
    __hip_bfloat162 h = __float22bfloat162_rn(make_float2(a, b));
    return *reinterpret_cast<unsigned*>(&h);
}
__device__ __forceinline__ void split_pair(float a, float b, unsigned &hi, unsigned &lo) {
    hi = pk2_bf16(a, b);
    float ha = __uint_as_float(hi << 16);
    float hb = __uint_as_float(hi & 0xffff0000u);
    lo = pk2_bf16(a - ha, b - hb);
}

struct RouterArgs {
    const float* cov;                      // [1024][512]
    const float* Wr1[3];                   // [512][256]
    const float* br1[3];                   // [256]
    const float* Wr2[3];                   // [256][7]
    const float* br2[3];                   // [7]
    const float* Wc[3];                    // [512][128]
    const float* bc[3];                    // [128]
    float* ws;
};

// grid (128, 3), block 768 (12 waves): 8 b's x one layer per block.
__global__ __launch_bounds__(768) void router_kernel(RouterArgs a) {
    const int l   = blockIdx.y;
    const int b0  = blockIdx.x * 8;
    const int tid = threadIdx.x;

    __shared__ float4 covs[8][COV_ / 4];   // 16 KB  [bb][k4]
    __shared__ float  part[4][3072];       // 48 KB  [ks][bb*384 + c]
    __shared__ float  hr[8][256];          // 8 KB
    __shared__ float  susage[ES_];
    if (tid < ES_) susage[tid] = 0.0f;

    for (int f = tid; f < 1024; f += 768) {
        const int bb = f >> 7, k4 = f & 127;
        covs[bb][k4] = ((const float4*)(a.cov + (size_t)(b0 + bb) * COV_))[k4];
    }
    __syncthreads();

    // Phase A: GEMV, 2 cols x 8 b's x 128 k's per thread
    {
        const int cp = tid % 192;
        const int ks = tid / 192;
        const int c0 = cp * 2;
        const float* __restrict__ Wp; int rs;
        if (c0 < 256) { Wp = a.Wr1[l] + c0;         rs = 256; }
        else          { Wp = a.Wc[l]  + (c0 - 256); rs = 128; }

        float acc0[8], acc1[8];
        #pragma unroll
        for (int bb = 0; bb < 8; ++bb) { acc0[bb] = 0.f; acc1[bb] = 0.f; }

        const int k4beg = ks * 32, k4end = k4beg + 32;
        #pragma unroll 2
        for (int k4 = k4beg; k4 < k4end; ++k4) {
            float2 w0 = *(const float2*)(Wp + (size_t)(4 * k4 + 0) * rs);
            float2 w1 = *(const float2*)(Wp + (size_t)(4 * k4 + 1) * rs);
            float2 w2 = *(const float2*)(Wp + (size_t)(4 * k4 + 2) * rs);
            float2 w3 = *(const float2*)(Wp + (size_t)(4 * k4 + 3) * rs);
            #pragma unroll
            for (int bb = 0; bb < 8; ++bb) {
                float4 cv = covs[bb][k4];
                acc0[bb] = fmaf(cv.x, w0.x, acc0[bb]);
                acc1[bb] = fmaf(cv.x, w0.y, acc1[bb]);
                acc0[bb] = fmaf(cv.y, w1.x, acc0[bb]);
                acc1[bb] = fmaf(cv.y, w1.y, acc1[bb]);
                acc0[bb] = fmaf(cv.z, w2.x, acc0[bb]);
                acc1[bb] = fmaf(cv.z, w2.y, acc1[bb]);
                acc0[bb] = fmaf(cv.w, w3.x, acc0[bb]);
                acc1[bb] = fmaf(cv.w, w3.y, acc1[bb]);
            }
        }
        #pragma unroll
        for (int bb = 0; bb < 8; ++bb)
            *(float2*)&part[ks][bb * 384 + c0] = make_float2(acc0[bb], acc1[bb]);
    }
    __syncthreads();

    // Reduce k-quarters
    {
        const int p0 = tid * 4;
        float4 s = {0.f, 0.f, 0.f, 0.f};
        #pragma unroll
        for (int ks = 0; ks < 4; ++ks) {
            float4 v = *(const float4*)&part[ks][p0];
            s.x += v.x; s.y += v.y; s.z += v.z; s.w += v.w;
        }
        const int bb = p0 / 384;
        const int c  = p0 % 384;
        const float sv[4] = {s.x, s.y, s.z, s.w};
        if (c < 256) {
            #pragma unroll
            for (int q = 0; q < 4; ++q)
                hr[bb][c + q] = fmaxf(sv[q] + a.br1[l][c + q], 0.0f);
        } else {
            #pragma unroll
            for (int q = 0; q < 4; ++q)
                a.ws[COVG_OFF + (size_t)(l * B_ + b0 + bb) * H_ + (c - 256 + q)] = sv[q] + a.bc[l][c - 256 + q];
        }
    }
    __syncthreads();

    // Phase B: router logits + softmax, one wave per b
    {
        const int wave = tid >> 6;
        const int lane = tid & 63;
        if (wave < 8) {
            const int bb = wave;
            const int o = lane >> 3;
            const int g = lane & 7;
            float p = 0.0f;
            if (o < ES_) {
                #pragma unroll
                for (int m = 0; m < 32; ++m) {
                    const int k = g * 32 + m;
                    p = fmaf(hr[bb][k], a.Wr2[l][k * ES_ + o], p);
                }
            }
            p += __shfl_xor(p, 1);
            p += __shfl_xor(p, 2);
            p += __shfl_xor(p, 4);
            const float lg = p + ((o < ES_) ? a.br2[l][o] : 0.0f);
            float v[ES_];
            #pragma unroll
            for (int oo = 0; oo < ES_; ++oo) v[oo] = __shfl(lg, oo * 8, 64);
            if (lane == 0) {
                const int b = b0 + bb;
                float mx = v[0];
                #pragma unroll
                for (int oo = 1; oo < ES_; ++oo) mx = fmaxf(mx, v[oo]);
                float ex[ES_]; float s = 0.0f;
                #pragma unroll
                for (int oo = 0; oo < ES_; ++oo) { ex[oo] = __expf(v[oo] - mx); s += ex[oo]; }
                const float inv = 0.7f / s;
                float* wout = a.ws + W_WS_OFF + (size_t)(l * B_ + b) * 8;
                wout[0] = 0.3f;
                #pragma unroll
                for (int oo = 0; oo < ES_; ++oo) {
                    const float rwv = ex[oo] * inv;
                    wout[1 + oo] = rwv;
                    atomicAdd(&susage[oo], rwv);
                }
            }
        }
    }
    __syncthreads();
    if (tid < ES_)
        a.ws[USAGE_OFF + (size_t)(l * 128 + blockIdx.x) * 8 + tid] = susage[tid];
}

struct MainArgs {
    const float* y_t;        // [1024][256]
    const float* y0;         // [1024][256]
    const int*   t;          // [1024]
    const float* emb[3];     // [1001][128]
    const float* W1;         // [8][2][128]
    const float* W2;         // [8][128][128]
    const float* W3;         // [8][128][128]
    const float* b_[3];      // [8][128]
    const float* W4;         // [128]
    const float* b4;         // [1]
    float* ws;
    float* out;              // [1024*256] + [1] load
};

// grid 1024, 1024 threads (16 waves), EXACTLY 160 KiB LDS -> 1 block/CU,
// 4 waves/SIMD. amdgpu_waves_per_eu(4,4) pins the allocator at 4 waves/EU
// -> up to 128 VGPR/thread. (R9: compiler sat at 64 VGPR and spilled the
// 80-reg inner-loop live set -> 385 MB scratch traffic. Code is IDENTICAL
// to R9 except this attribute — single-variable experiment.)
__global__ __launch_bounds__(1024)
__attribute__((amdgpu_waves_per_eu(4, 4)))
void main_kernel(MainArgs a) {
    __shared__ __align__(16) char smem[163840];
    unsigned short* Ahi = (unsigned short*)smem;             // 65536 B [tok][swz chunk]
    unsigned short* Alo = (unsigned short*)(smem + 65536);   // 65536 B
    // Wt buf p: base 131072 + p*16384; hi 4096 shorts, lo at +4096 shorts

    const int tid  = threadIdx.x;
    const int b    = blockIdx.x;
    const int lane = tid & 63;
    const int w    = tid >> 6;      // 0..15
    const int wm   = w >> 1;        // 0..7: token block (32)
    const int wn   = w & 1;         // 0..1: n block (64)
    const int nl   = lane & 15;
    const int quad = lane >> 4;
    const int tb   = a.t[b];

    // load-balance scalar: block 0 wave 0 reduces router partials
    if (b == 0 && tid < 64) {
        float d2 = 0.0f;
        if (tid < 21) {
            const int l = tid / 7, o = tid % 7;
            float s = 0.0f;
            for (int bx = 0; bx < 128; ++bx)
                s += a.ws[USAGE_OFF + (size_t)(l * 128 + bx) * 8 + o];
            const float u = s * (1.0f / (float)B_);
            const float d = u - (1.0f / (float)ES_);
            d2 = d * d;
        }
        float tot = 0.0f;
        #pragma unroll
        for (int i = 0; i < 21; ++i) tot += __shfl(d2, i, 64);
        if (tid == 0) a.out[B_ * S_] = tot * (1.0f / (float)ES_);
    }

    // L1 coefficients -> buf0-aliased LDS (consumed before first Wt store)
    float* L1f = (float*)(smem + 131072);   // A[128],B[128],C[128]
    if (tid < 128) {
        const int j = tid;
        const float* wv = a.ws + W_WS_OFF + (size_t)b * 8;   // layer 0
        float s0 = 0.f, s1 = 0.f, bm = 0.f;
        #pragma unroll
        for (int e = 0; e < E_; ++e) {
            s0 = fmaf(wv[e], a.W1[e * 256 + j], s0);
            s1 = fmaf(wv[e], a.W1[e * 256 + 128 + j], s1);
            bm = fmaf(wv[e], a.b_[0][e * H_ + j], bm);
        }
        const float covg = a.ws[COVG_OFF + (size_t)b * H_ + j];
        const float gp = a.emb[0][tb * H_ + j] * (1.0f + covg);
        L1f[j]       = gp * s0;
        L1f[128 + j] = gp * s1;
        L1f[256 + j] = gp * bm;
    }
    __syncthreads();

    // ---- layer 1: tok = tid>>2, 4 threads/token, swizzled At writes ----
    {
        const int tok = tid >> 2;
        const float x0 = a.y_t[b * S_ + tok];
        const float x1 = a.y0[b * S_ + tok];
        const int tsw = tok & 15;
        #pragma unroll
        for (int g = 0; g < 4; ++g) {
            const int c  = (tid & 3) * 4 + g;     // chunk 0..15 (8 k's each)
            const int jb = c * 8;
            unsigned hp[4], lp[4];
            #pragma unroll
            for (int p = 0; p < 4; ++p) {
                const int j0 = jb + 2 * p;
                float m0 = fmaf(x0, L1f[j0],     fmaf(x1, L1f[128 + j0],     L1f[256 + j0]));
                float m1 = fmaf(x0, L1f[j0 + 1], fmaf(x1, L1f[128 + j0 + 1], L1f[256 + j0 + 1]));
                split_pair(softplus_f(m0), softplus_f(m1), hp[p], lp[p]);
            }
            const int off = tok * 128 + ((c ^ tsw) << 3);
            *(uint4*)&Ahi[off] = make_uint4(hp[0], hp[1], hp[2], hp[3]);
            *(uint4*)&Alo[off] = make_uint4(lp[0], lp[1], lp[2], lp[3]);
        }
    }

    // Weff builder thread mapping: col bj, k-sub bkg (4 k's)
    const int bj   = tid & 127;
    const int bkg  = tid >> 7;            // 0..7
    const int bq   = bkg >> 1;            // chunk (8 k's) within 32-k tile
    const int bwoff = bj * 32 + ((bq ^ ((bj >> 1) & 3)) << 3) + (bkg & 1) * 4;

    for (int L = 0; L < 2; ++L) {
        const float* __restrict__ Wg = L ? a.W3 : a.W2;
        const int li = L + 1;
        const float* wvp = a.ws + W_WS_OFF + (size_t)(li * B_ + b) * 8;
        float we[E_];
        #pragma unroll
        for (int e = 0; e < E_; ++e) we[e] = wvp[e];

        f32x4 acc[2][4];
        #pragma unroll
        for (int mt = 0; mt < 2; ++mt)
            #pragma unroll
            for (int nt = 0; nt < 4; ++nt)
                acc[mt][nt] = (f32x4){0.f, 0.f, 0.f, 0.f};

        unsigned bh[2], blo_[2];
        auto build = [&](int kc) {
            float bacc[4] = {0.f, 0.f, 0.f, 0.f};
            const float* base = Wg + (size_t)(kc * 32 + bkg * 4) * H_ + bj;
            #pragma unroll
            for (int e = 0; e < E_; ++e) {
                const float* p = base + (size_t)e * (H_ * H_);
                const float wE = we[e];
                #pragma unroll
                for (int i = 0; i < 4; ++i)
                    bacc[i] = fmaf(wE, p[i * H_], bacc[i]);
            }
            split_pair(bacc[0], bacc[1], bh[0], blo_[0]);
            split_pair(bacc[2], bacc[3], bh[1], blo_[1]);
        };

        build(0);
        __syncthreads();   // At writes (L1 / epilogue-2) + prior buf reads done
        {
            unsigned short* wtH = (unsigned short*)(smem + 131072);
            *(uint2*)&wtH[bwoff]        = make_uint2(bh[0], bh[1]);
            *(uint2*)&wtH[4096 + bwoff] = make_uint2(blo_[0], blo_[1]);
        }
        __syncthreads();   // buf0 visible

        for (int kc = 0; kc < 4; ++kc) {
            unsigned short* wtH = (unsigned short*)(smem + 131072 + (kc & 1) * 16384);
            unsigned short* wtL = wtH + 4096;
            const int c = kc * 4 + quad;

            bf16x8 Af[2], Al[2], Bf[4], Bl[4];
            #pragma unroll
            for (int mt = 0; mt < 2; ++mt) {
                const int tok = wm * 32 + mt * 16 + nl;
                const int off = tok * 128 + ((c ^ (tok & 15)) << 3);
                Af[mt] = *(const bf16x8*)&Ahi[off];
                Al[mt] = *(const bf16x8*)&Alo[off];
            }
            #pragma unroll
            for (int nt = 0; nt < 4; ++nt) {
                const int n = wn * 64 + nt * 16 + nl;
                const int off = n * 32 + ((quad ^ ((n >> 1) & 3)) << 3);
                Bf[nt] = *(const bf16x8*)&wtH[off];
                Bl[nt] = *(const bf16x8*)&wtL[off];
            }
            #pragma unroll
            for (int mt = 0; mt < 2; ++mt)
                #pragma unroll
                for (int nt = 0; nt < 4; ++nt) {
                    acc[mt][nt] = __builtin_amdgcn_mfma_f32_16x16x32_bf16(Af[mt], Bf[nt], acc[mt][nt], 0, 0, 0);
                    acc[mt][nt] = __builtin_amdgcn_mfma_f32_16x16x32_bf16(Af[mt], Bl[nt], acc[mt][nt], 0, 0, 0);
                    acc[mt][nt] = __builtin_amdgcn_mfma_f32_16x16x32_bf16(Al[mt], Bf[nt], acc[mt][nt], 0, 0, 0);
                }

            if (kc < 3) {
                build(kc + 1);   // global loads overlap MFMA; store into other buf
                unsigned short* dH = (unsigned short*)(smem + 131072 + ((kc + 1) & 1) * 16384);
                *(uint2*)&dH[bwoff]        = make_uint2(bh[0], bh[1]);
                *(uint2*)&dH[4096 + bwoff] = make_uint2(blo_[0], blo_[1]);
            }
            __syncthreads();
        }

        // ---- epilogue params computed ON DEMAND (transient registers) ----
        float gpx[4], gpbx[4];
        #pragma unroll
        for (int nt = 0; nt < 4; ++nt) {
            const int n = wn * 64 + nt * 16 + nl;
            const float covg  = a.ws[COVG_OFF + (size_t)(li * B_ + b) * H_ + n];
            const float gamma = a.emb[li][tb * H_ + n];
            const float gp = gamma * (1.0f + covg);
            float bm = 0.0f;
            #pragma unroll
            for (int e = 0; e < E_; ++e) bm = fmaf(we[e], a.b_[li][e * H_ + n], bm);
            gpx[nt]  = gp;
            gpbx[nt] = gp * bm;
        }

        if (L == 0) {
            // epilogue layer-2 -> At (swizzled); C layout: n=nl(+16nt), tok=quad*4+r(+16mt)
            #pragma unroll
            for (int nt = 0; nt < 4; ++nt) {
                const int n = wn * 64 + nt * 16 + nl;
                const float gp = gpx[nt], gpb = gpbx[nt];
                const int nc = n >> 3, np = n & 7;
                #pragma unroll
                for (int mt = 0; mt < 2; ++mt) {
                    const int tok0 = wm * 32 + mt * 16 + quad * 4;
                    #pragma unroll
                    for (int rp = 0; rp < 2; ++rp) {
                        const float h0 = softplus_f(fmaf(gp, acc[mt][nt][2 * rp],     gpb));
                        const float h1 = softplus_f(fmaf(gp, acc[mt][nt][2 * rp + 1], gpb));
                        unsigned hh, ll;
                        split_pair(h0, h1, hh, ll);
                        const int t0 = tok0 + 2 * rp;
                        const int o0 = t0 * 128       + ((nc ^ (t0 & 15))       << 3) + np;
                        const int o1 = (t0 + 1) * 128 + ((nc ^ ((t0 + 1) & 15)) << 3) + np;
                        Ahi[o0] = (unsigned short)hh;
                        Ahi[o1] = (unsigned short)(hh >> 16);
                        Alo[o0] = (unsigned short)ll;
                        Alo[o1] = (unsigned short)(ll >> 16);
                    }
                }
            }
            // next layer's build(0)+barrier orders these writes before kc0 reads
        } else {
            // epilogue layer-3 fused with h3 @ W4
            float po[2][4];
            #pragma unroll
            for (int mt = 0; mt < 2; ++mt)
                #pragma unroll
                for (int r = 0; r < 4; ++r) po[mt][r] = 0.0f;
            #pragma unroll
            for (int nt = 0; nt < 4; ++nt) {
                const int n = wn * 64 + nt * 16 + nl;
                const float gp = gpx[nt], gpb = gpbx[nt];
                const float w4 = a.W4[n];
                #pragma unroll
                for (int mt = 0; mt < 2; ++mt)
                    #pragma unroll
                    for (int r = 0; r < 4; ++r) {
                        const float h = softplus_f(fmaf(gp, acc[mt][nt][r], gpb));
                        po[mt][r] = fmaf(h, w4, po[mt][r]);
                    }
            }
            #pragma unroll
            for (int mt = 0; mt < 2; ++mt)
                #pragma unroll
                for (int r = 0; r < 4; ++r) {
                    po[mt][r] += __shfl_xor(po[mt][r], 1);
                    po[mt][r] += __shfl_xor(po[mt][r], 2);
                    po[mt][r] += __shfl_xor(po[mt][r], 4);
                    po[mt][r] += __shfl_xor(po[mt][r], 8);
                }
            float* pos = (float*)(smem + 131072);   // buf0 region (not read at kc=3)
            if (nl == 0) {
                #pragma unroll
                for (int mt = 0; mt < 2; ++mt)
                    #pragma unroll
                    for (int r = 0; r < 4; ++r)
                        pos[(wm * 32 + mt * 16 + quad * 4 + r) * 2 + wn] = po[mt][r];
            }
            __syncthreads();
            if (tid < 256)
                a.out[b * S_ + tid] = pos[2 * tid] + pos[2 * tid + 1] + a.b4[0];
        }
    }
}

extern "C" void kernel_launch(void* const* d_in, const int* in_sizes, int n_in,
                              void* d_out, int out_size, void* d_ws, size_t ws_size,
                              hipStream_t stream) {
    (void)in_sizes; (void)n_in; (void)out_size; (void)ws_size;

    RouterArgs ra;
    ra.cov = (const float*)d_in[2];
    ra.ws  = (float*)d_ws;

    MainArgs ma;
    ma.y_t = (const float*)d_in[0];
    ma.y0  = (const float*)d_in[1];
    ma.t   = (const int*)d_in[3];
    for (int l = 0; l < 3; ++l) {
        const int base = 4 + l * 9;
        ma.emb[l] = (const float*)d_in[base + 0];
        ma.b_[l]  = (const float*)d_in[base + 2];
        ra.Wc[l]  = (const float*)d_in[base + 3];
        ra.bc[l]  = (const float*)d_in[base + 4];
        ra.Wr1[l] = (const float*)d_in[base + 5];
        ra.br1[l] = (const float*)d_in[base + 6];
        ra.Wr2[l] = (const float*)d_in[base + 7];
        ra.br2[l] = (const float*)d_in[base + 8];
    }
    ma.W1 = (const float*)d_in[4 + 0 * 9 + 1];
    ma.W2 = (const float*)d_in[4 + 1 * 9 + 1];
    ma.W3 = (const float*)d_in[4 + 2 * 9 + 1];
    ma.W4 = (const float*)d_in[31];
    ma.b4 = (const float*)d_in[32];
    ma.ws  = (float*)d_ws;
    ma.out = (float*)d_out;

    router_kernel<<<dim3(128, 3, 1), 768, 0, stream>>>(ra);
    main_kernel<<<dim3(1024, 1, 1), 1024, 0, stream>>>(ma);
}

// Round 11
// 286.654 us; speedup vs baseline: 1.2258x; 1.2258x over previous
//
#include <hip/hip_runtime.h>
#include <hip/hip_bf16.h>
#include <math.h>

// Problem constants
#define B_    1024
#define S_    256
#define COV_  512
#define H_    128
#define E_    8
#define ES_   7

// ws layout (floats)
#define W_WS_OFF   0                       // [3][1024][8]
#define COVG_OFF   24576                   // [3][1024][128]
#define USAGE_OFF  417792                  // [3][128][8] per-router-block partials

#define WT_STRIDE  40                      // 32 k + 8 pad (bf16), row = 80 B (16B aligned)

typedef __attribute__((ext_vector_type(8))) short bf16x8;  // 8 bf16 = 4 VGPRs (MFMA A/B frag)
typedef __attribute__((ext_vector_type(4))) float f32x4;   // MFMA C/D frag

// Fast softplus: 2 HW transcendentals (v_exp_f32 / v_log_f32) + few VALU.
__device__ __forceinline__ float softplus_f(float x) {
    return fmaxf(x, 0.0f) + __logf(1.0f + __expf(-fabsf(x)));
}

// v_cvt_pk_bf16_f32: pack two fp32 -> two bf16 (RNE).
__device__ __forceinline__ unsigned pk2_bf16(float a, float b) {
    __hip_bfloat162 h = __float22bfloat162_rn(make_float2(a, b));
    return *reinterpret_cast<unsigned*>(&h);
}
__device__ __forceinline__ void split_pair(float a, float b, unsigned &hi, unsigned &lo) {
    hi = pk2_bf16(a, b);
    float ha = __uint_as_float(hi << 16);
    float hb = __uint_as_float(hi & 0xffff0000u);
    lo = pk2_bf16(a - ha, b - hb);
}

struct RouterArgs {
    const float* cov;                      // [1024][512]
    const float* Wr1[3];                   // [512][256]
    const float* br1[3];                   // [256]
    const float* Wr2[3];                   // [256][7]
    const float* br2[3];                   // [7]
    const float* Wc[3];                    // [512][128]
    const float* bc[3];                    // [128]
    float* ws;
};

// grid (128, 3), block 768 (12 waves): 8 b's x one layer per block.
// Register-tiled GEMV (R7 structure); usage as per-block partials.
__global__ __launch_bounds__(768) void router_kernel(RouterArgs a) {
    const int l   = blockIdx.y;
    const int b0  = blockIdx.x * 8;
    const int tid = threadIdx.x;

    __shared__ float4 covs[8][COV_ / 4];   // 16 KB  [bb][k4]
    __shared__ float  part[4][3072];       // 48 KB  [ks][bb*384 + c]
    __shared__ float  hr[8][256];          // 8 KB
    __shared__ float  susage[ES_];
    if (tid < ES_) susage[tid] = 0.0f;

    for (int f = tid; f < 1024; f += 768) {
        const int bb = f >> 7, k4 = f & 127;
        covs[bb][k4] = ((const float4*)(a.cov + (size_t)(b0 + bb) * COV_))[k4];
    }
    __syncthreads();

    // Phase A: GEMV, 2 cols x 8 b's x 128 k's per thread
    {
        const int cp = tid % 192;
        const int ks = tid / 192;
        const int c0 = cp * 2;
        const float* __restrict__ Wp; int rs;
        if (c0 < 256) { Wp = a.Wr1[l] + c0;         rs = 256; }
        else          { Wp = a.Wc[l]  + (c0 - 256); rs = 128; }

        float acc0[8], acc1[8];
        #pragma unroll
        for (int bb = 0; bb < 8; ++bb) { acc0[bb] = 0.f; acc1[bb] = 0.f; }

        const int k4beg = ks * 32, k4end = k4beg + 32;
        #pragma unroll 2
        for (int k4 = k4beg; k4 < k4end; ++k4) {
            float2 w0 = *(const float2*)(Wp + (size_t)(4 * k4 + 0) * rs);
            float2 w1 = *(const float2*)(Wp + (size_t)(4 * k4 + 1) * rs);
            float2 w2 = *(const float2*)(Wp + (size_t)(4 * k4 + 2) * rs);
            float2 w3 = *(const float2*)(Wp + (size_t)(4 * k4 + 3) * rs);
            #pragma unroll
            for (int bb = 0; bb < 8; ++bb) {
                float4 cv = covs[bb][k4];
                acc0[bb] = fmaf(cv.x, w0.x, acc0[bb]);
                acc1[bb] = fmaf(cv.x, w0.y, acc1[bb]);
                acc0[bb] = fmaf(cv.y, w1.x, acc0[bb]);
                acc1[bb] = fmaf(cv.y, w1.y, acc1[bb]);
                acc0[bb] = fmaf(cv.z, w2.x, acc0[bb]);
                acc1[bb] = fmaf(cv.z, w2.y, acc1[bb]);
                acc0[bb] = fmaf(cv.w, w3.x, acc0[bb]);
                acc1[bb] = fmaf(cv.w, w3.y, acc1[bb]);
            }
        }
        #pragma unroll
        for (int bb = 0; bb < 8; ++bb)
            *(float2*)&part[ks][bb * 384 + c0] = make_float2(acc0[bb], acc1[bb]);
    }
    __syncthreads();

    // Reduce k-quarters
    {
        const int p0 = tid * 4;
        float4 s = {0.f, 0.f, 0.f, 0.f};
        #pragma unroll
        for (int ks = 0; ks < 4; ++ks) {
            float4 v = *(const float4*)&part[ks][p0];
            s.x += v.x; s.y += v.y; s.z += v.z; s.w += v.w;
        }
        const int bb = p0 / 384;
        const int c  = p0 % 384;
        const float sv[4] = {s.x, s.y, s.z, s.w};
        if (c < 256) {
            #pragma unroll
            for (int q = 0; q < 4; ++q)
                hr[bb][c + q] = fmaxf(sv[q] + a.br1[l][c + q], 0.0f);
        } else {
            #pragma unroll
            for (int q = 0; q < 4; ++q)
                a.ws[COVG_OFF + (size_t)(l * B_ + b0 + bb) * H_ + (c - 256 + q)] = sv[q] + a.bc[l][c - 256 + q];
        }
    }
    __syncthreads();

    // Phase B: router logits + softmax, one wave per b
    {
        const int wave = tid >> 6;
        const int lane = tid & 63;
        if (wave < 8) {
            const int bb = wave;
            const int o = lane >> 3;
            const int g = lane & 7;
            float p = 0.0f;
            if (o < ES_) {
                #pragma unroll
                for (int m = 0; m < 32; ++m) {
                    const int k = g * 32 + m;
                    p = fmaf(hr[bb][k], a.Wr2[l][k * ES_ + o], p);
                }
            }
            p += __shfl_xor(p, 1);
            p += __shfl_xor(p, 2);
            p += __shfl_xor(p, 4);
            const float lg = p + ((o < ES_) ? a.br2[l][o] : 0.0f);
            float v[ES_];
            #pragma unroll
            for (int oo = 0; oo < ES_; ++oo) v[oo] = __shfl(lg, oo * 8, 64);
            if (lane == 0) {
                const int b = b0 + bb;
                float mx = v[0];
                #pragma unroll
                for (int oo = 1; oo < ES_; ++oo) mx = fmaxf(mx, v[oo]);
                float ex[ES_]; float s = 0.0f;
                #pragma unroll
                for (int oo = 0; oo < ES_; ++oo) { ex[oo] = __expf(v[oo] - mx); s += ex[oo]; }
                const float inv = 0.7f / s;
                float* wout = a.ws + W_WS_OFF + (size_t)(l * B_ + b) * 8;
                wout[0] = 0.3f;
                #pragma unroll
                for (int oo = 0; oo < ES_; ++oo) {
                    const float rwv = ex[oo] * inv;
                    wout[1 + oo] = rwv;
                    atomicAdd(&susage[oo], rwv);
                }
            }
        }
    }
    __syncthreads();
    if (tid < ES_)
        a.ws[USAGE_OFF + (size_t)(l * 128 + blockIdx.x) * 8 + tid] = susage[tid];
}

struct MainArgs {
    const float* y_t;        // [1024][256]
    const float* y0;         // [1024][256]
    const int*   t;          // [1024]
    const float* emb[3];     // [1001][128]
    const float* W1;         // [8][2][128]
    const float* W2;         // [8][128][128]
    const float* W3;         // [8][128][128]
    const float* b_[3];      // [8][128]
    const float* W4;         // [128]
    const float* b4;         // [1]
    float* ws;
    float* out;              // [1024*256] + [1] load
};

// grid 1024, 1024 threads (16 waves), 154 KB LDS -> 1 block/CU, 4 waves/SIMD.
// EXACT R7 loop structure (padded single-buffer Wt, 2 barriers/kc, params in
// LDS, build-after-MFMA — compiled spill-free at 64 VGPR, 148.6 us) with ONE
// change: XOR-swizzled un-padded At (chunk ^= tok&15), validated correct in
// R8-R10, cuts SQ_LDS_BANK_CONFLICT 9.96M -> ~3.7M. (R8/R9 ping-pong lesson:
// any restructure that grows the inner live set past what the compiler fits
// in 64 arch-VGPRs triggers scratch spill, 154-230 MB HBM, ~1.5x regression.)
__global__ __launch_bounds__(1024, 4) void main_kernel(MainArgs a) {
    __shared__ unsigned short Ahi[256 * 128];            // 65536 B [tok][swz chunk<<3 | j]
    __shared__ unsigned short Alo[256 * 128];            // 65536 B
    __shared__ unsigned short WtBuf[2][128 * WT_STRIDE]; // 20480 B (hi, lo); aliases L1f / pos
    __shared__ float GPs[2][128];    // gamma*(1+covg) for layers 2,3
    __shared__ float GPBs[2][128];   // GPs * bmix
    __shared__ float W4s[128];

    const int tid  = threadIdx.x;
    const int b    = blockIdx.x;
    const int lane = tid & 63;
    const int w    = tid >> 6;      // 0..15
    const int wm   = w >> 1;        // 0..7: token block (32)
    const int wn   = w & 1;         // 0..1: n block (64)
    const int nl   = lane & 15;
    const int quad = lane >> 4;
    const int tb   = a.t[b];

    // load-balance scalar: block 0 wave 0 reduces router partials
    if (b == 0 && tid < 64) {
        float d2 = 0.0f;
        if (tid < 21) {
            const int l = tid / 7, o = tid % 7;
            float s = 0.0f;
            for (int bx = 0; bx < 128; ++bx)
                s += a.ws[USAGE_OFF + (size_t)(l * 128 + bx) * 8 + o];
            const float u = s * (1.0f / (float)B_);
            const float d = u - (1.0f / (float)ES_);
            d2 = d * d;
        }
        float tot = 0.0f;
        #pragma unroll
        for (int i = 0; i < 21; ++i) tot += __shfl(d2, i, 64);
        if (tid == 0) a.out[B_ * S_] = tot * (1.0f / (float)ES_);
    }

    float* L1f = (float*)WtBuf;     // [0:128)=A, [128:256)=B, [256:384)=C coeffs

    // ---- prologue: per-layer modulation vectors (R7 exact) ----
    if (tid < 384) {
        const int l = tid >> 7, j = tid & 127;
        const float* wv = a.ws + W_WS_OFF + (size_t)(l * B_ + b) * 8;
        const float gamma = a.emb[l][tb * H_ + j];
        const float covg  = a.ws[COVG_OFF + (size_t)(l * B_ + b) * H_ + j];
        const float gp = gamma * (1.0f + covg);
        const float* bl = a.b_[l];
        float bm = 0.0f;
        #pragma unroll
        for (int e = 0; e < E_; ++e) bm = fmaf(wv[e], bl[e * H_ + j], bm);
        if (l == 0) {
            float s0 = 0.0f, s1 = 0.0f;
            #pragma unroll
            for (int e = 0; e < E_; ++e) {
                s0 = fmaf(wv[e], a.W1[e * 256 + j], s0);
                s1 = fmaf(wv[e], a.W1[e * 256 + 128 + j], s1);
            }
            L1f[j]       = gp * s0;
            L1f[128 + j] = gp * s1;
            L1f[256 + j] = gp * bm;
        } else {
            GPs[l - 1][j]  = gp;
            GPBs[l - 1][j] = gp * bm;
        }
    }
    if (tid < 128) W4s[tid] = a.W4[tid];
    __syncthreads();

    // ---- layer 1: 4 threads/token, swizzled At writes ----
    {
        const int tok = tid >> 2;
        const float x0 = a.y_t[b * S_ + tok];
        const float x1 = a.y0[b * S_ + tok];
        const int tsw = tok & 15;
        #pragma unroll
        for (int g = 0; g < 4; ++g) {
            const int c  = (tid & 3) * 4 + g;     // chunk 0..15 (8 k's each)
            const int jb = c * 8;
            unsigned hp[4], lp[4];
            #pragma unroll
            for (int p = 0; p < 4; ++p) {
                const int j0 = jb + 2 * p;
                float m0 = fmaf(x0, L1f[j0],     fmaf(x1, L1f[128 + j0],     L1f[256 + j0]));
                float m1 = fmaf(x0, L1f[j0 + 1], fmaf(x1, L1f[128 + j0 + 1], L1f[256 + j0 + 1]));
                split_pair(softplus_f(m0), softplus_f(m1), hp[p], lp[p]);
            }
            const int off = tok * 128 + ((c ^ tsw) << 3);
            *(uint4*)&Ahi[off] = make_uint4(hp[0], hp[1], hp[2], hp[3]);
            *(uint4*)&Alo[off] = make_uint4(lp[0], lp[1], lp[2], lp[3]);
        }
    }
    // (first chunk barrier below synchronizes At)

    // Weff builder thread mapping: col bj, k-sub bkg (4 k's) — R7 exact
    const int bj  = tid & 127;
    const int bkg = tid >> 7;             // 0..7

    for (int L = 0; L < 2; ++L) {
        const float* __restrict__ Wg = L ? a.W3 : a.W2;
        const int li = L + 1;
        const float* wvp = a.ws + W_WS_OFF + (size_t)(li * B_ + b) * 8;
        float we[E_];
        #pragma unroll
        for (int e = 0; e < E_; ++e) we[e] = wvp[e];

        f32x4 acc[2][4];
        #pragma unroll
        for (int mt = 0; mt < 2; ++mt)
            #pragma unroll
            for (int nt = 0; nt < 4; ++nt)
                acc[mt][nt] = (f32x4){0.f, 0.f, 0.f, 0.f};

        unsigned bh[2], blo_[2];
        auto build = [&](int kc) {
            float bacc[4] = {0.f, 0.f, 0.f, 0.f};
            const float* base = Wg + (size_t)(kc * 32 + bkg * 4) * H_ + bj;
            #pragma unroll
            for (int e = 0; e < E_; ++e) {
                const float* p = base + (size_t)e * (H_ * H_);
                const float wE = we[e];
                #pragma unroll
                for (int i = 0; i < 4; ++i)
                    bacc[i] = fmaf(wE, p[i * H_], bacc[i]);
            }
            split_pair(bacc[0], bacc[1], bh[0], blo_[0]);
            split_pair(bacc[2], bacc[3], bh[1], blo_[1]);
        };

        build(0);

        for (int kc = 0; kc < 4; ++kc) {
            __syncthreads();   // prev GEMM done reading Wt; At writes visible (kc==0)
            *(uint2*)&WtBuf[0][bj * WT_STRIDE + bkg * 4] = make_uint2(bh[0], bh[1]);
            *(uint2*)&WtBuf[1][bj * WT_STRIDE + bkg * 4] = make_uint2(blo_[0], blo_[1]);
            __syncthreads();

            // GEMM k-step (K=32)
            const int c = kc * 4 + quad;   // At chunk index
            bf16x8 Af[2], Al[2], Bf[4], Bl[4];
            #pragma unroll
            for (int mt = 0; mt < 2; ++mt) {
                const int tok = wm * 32 + mt * 16 + nl;
                const int off = tok * 128 + ((c ^ (tok & 15)) << 3);
                Af[mt] = *(const bf16x8*)&Ahi[off];
                Al[mt] = *(const bf16x8*)&Alo[off];
            }
            #pragma unroll
            for (int nt = 0; nt < 4; ++nt) {
                const int row = (wn * 64 + nt * 16 + nl) * WT_STRIDE + quad * 8;
                Bf[nt] = *(const bf16x8*)&WtBuf[0][row];
                Bl[nt] = *(const bf16x8*)&WtBuf[1][row];
            }
            #pragma unroll
            for (int mt = 0; mt < 2; ++mt)
                #pragma unroll
                for (int nt = 0; nt < 4; ++nt) {
                    acc[mt][nt] = __builtin_amdgcn_mfma_f32_16x16x32_bf16(Af[mt], Bf[nt], acc[mt][nt], 0, 0, 0);
                    acc[mt][nt] = __builtin_amdgcn_mfma_f32_16x16x32_bf16(Af[mt], Bl[nt], acc[mt][nt], 0, 0, 0);
                    acc[mt][nt] = __builtin_amdgcn_mfma_f32_16x16x32_bf16(Al[mt], Bf[nt], acc[mt][nt], 0, 0, 0);
                }

            if (kc < 3) build(kc + 1);
        }
        __syncthreads();   // all GEMM reads of At / Wt done

        if (L == 0) {
            // epilogue layer-2 -> At (swizzled); C layout: n=nl(+16nt), tok=quad*4+r(+16mt)
            #pragma unroll
            for (int nt = 0; nt < 4; ++nt) {
                const int n = wn * 64 + nt * 16 + nl;
                const float gp = GPs[0][n], gpb = GPBs[0][n];
                const int nc = n >> 3, np = n & 7;
                #pragma unroll
                for (int mt = 0; mt < 2; ++mt) {
                    const int tok0 = wm * 32 + mt * 16 + quad * 4;
                    #pragma unroll
                    for (int rp = 0; rp < 2; ++rp) {
                        const float h0 = softplus_f(fmaf(gp, acc[mt][nt][2 * rp],     gpb));
                        const float h1 = softplus_f(fmaf(gp, acc[mt][nt][2 * rp + 1], gpb));
                        unsigned hh, ll;
                        split_pair(h0, h1, hh, ll);
                        const int t0 = tok0 + 2 * rp;
                        const int o0 = t0 * 128       + ((nc ^ (t0 & 15))       << 3) + np;
                        const int o1 = (t0 + 1) * 128 + ((nc ^ ((t0 + 1) & 15)) << 3) + np;
                        Ahi[o0] = (unsigned short)hh;
                        Ahi[o1] = (unsigned short)(hh >> 16);
                        Alo[o0] = (unsigned short)ll;
                        Alo[o1] = (unsigned short)(ll >> 16);
                    }
                }
            }
            // next layer's build(0)+barrier orders these writes before kc0 reads
        } else {
            // epilogue layer-3 fused with h3 @ W4
            float po[2][4];
            #pragma unroll
            for (int mt = 0; mt < 2; ++mt)
                #pragma unroll
                for (int r = 0; r < 4; ++r) po[mt][r] = 0.0f;
            #pragma unroll
            for (int nt = 0; nt < 4; ++nt) {
                const int n = wn * 64 + nt * 16 + nl;
                const float gp = GPs[1][n], gpb = GPBs[1][n], w4 = W4s[n];
                #pragma unroll
                for (int mt = 0; mt < 2; ++mt)
                    #pragma unroll
                    for (int r = 0; r < 4; ++r) {
                        const float h = softplus_f(fmaf(gp, acc[mt][nt][r], gpb));
                        po[mt][r] = fmaf(h, w4, po[mt][r]);
                    }
            }
            #pragma unroll
            for (int mt = 0; mt < 2; ++mt)
                #pragma unroll
                for (int r = 0; r < 4; ++r) {
                    po[mt][r] += __shfl_xor(po[mt][r], 1);
                    po[mt][r] += __shfl_xor(po[mt][r], 2);
                    po[mt][r] += __shfl_xor(po[mt][r], 4);
                    po[mt][r] += __shfl_xor(po[mt][r], 8);
                }
            float* pos = (float*)WtBuf;   // Wt free after post-loop barrier
            if (nl == 0) {
                #pragma unroll
                for (int mt = 0; mt < 2; ++mt)
                    #pragma unroll
                    for (int r = 0; r < 4; ++r)
                        pos[(wm * 32 + mt * 16 + quad * 4 + r) * 2 + wn] = po[mt][r];
            }
            __syncthreads();
            if (tid < 256)
                a.out[b * S_ + tid] = pos[2 * tid] + pos[2 * tid + 1] + a.b4[0];
        }
    }
}

extern "C" void kernel_launch(void* const* d_in, const int* in_sizes, int n_in,
                              void* d_out, int out_size, void* d_ws, size_t ws_size,
                              hipStream_t stream) {
    (void)in_sizes; (void)n_in; (void)out_size; (void)ws_size;

    RouterArgs ra;
    ra.cov = (const float*)d_in[2];
    ra.ws  = (float*)d_ws;

    MainArgs ma;
    ma.y_t = (const float*)d_in[0];
    ma.y0  = (const float*)d_in[1];
    ma.t   = (const int*)d_in[3];
    for (int l = 0; l < 3; ++l) {
        const int base = 4 + l * 9;
        ma.emb[l] = (const float*)d_in[base + 0];
        ma.b_[l]  = (const float*)d_in[base + 2];
        ra.Wc[l]  = (const float*)d_in[base + 3];
        ra.bc[l]  = (const float*)d_in[base + 4];
        ra.Wr1[l] = (const float*)d_in[base + 5];
        ra.br1[l] = (const float*)d_in[base + 6];
        ra.Wr2[l] = (const float*)d_in[base + 7];
        ra.br2[l] = (const float*)d_in[base + 8];
    }
    ma.W1 = (const float*)d_in[4 + 0 * 9 + 1];
    ma.W2 = (const float*)d_in[4 + 1 * 9 + 1];
    ma.W3 = (const float*)d_in[4 + 2 * 9 + 1];
    ma.W4 = (const float*)d_in[31];
    ma.b4 = (const float*)d_in[32];
    ma.ws  = (float*)d_ws;
    ma.out = (float*)d_out;

    router_kernel<<<dim3(128, 3, 1), 768, 0, stream>>>(ra);
    main_kernel<<<dim3(1024, 1, 1), 1024, 0, stream>>>(ma);
}